// Round 4
// baseline (9782.949 us; speedup 1.0000x reference)
//
#include <hip/hip_runtime.h>
#include <math.h>

// ---------------------------------------------------------------------------
// MSDeformAttn encoder, 6 layers. Round 3: resubmit of round-2 kernel
// (container failed before execution — no evidence against it yet).
// fp32 everywhere, workspace 156MB via lifetime aliasing.
//
// B=8, D=256, NH=8, DH=32, NL=4, NP=4, LQ=5440 (levels 64^2,32^2,16^2,8^2),
// DFF=1024. NTOK = B*LQ = 43520.
//
// Buffer plan (floats per token):
//   X      -> d_out (fully rewritten by flatten each call; final LN2 output
//             is X, so d_out ends up correct automatically)
//   ws+0      : Pos   (256)   persistent
//   ws+256*N  : T/val (256)   val dead after msdeform; T written after
//   ws+512*N  : off/acc/Hchunk (256)  off->acc alias safe (same-thread RMW);
//             FFN hidden processed in 4 chunks of 10880 rows
//   ws+768*N  : att   (128)
// Total ws = NTOK*896*4 = 155,975,680 B (~156 MB).
// ---------------------------------------------------------------------------

#define NTOK 43520
#define LQc  5440
#define Dc   256

// ---------------- flatten: (B,C,H,W) -> (B, HW, C) with LDS transpose -------
__global__ __launch_bounds__(256) void flatten_level_kernel(
    const float* __restrict__ src, const float* __restrict__ pse,
    const float* __restrict__ lev, float* __restrict__ x, float* __restrict__ pos,
    int HW, int start)
{
  __shared__ float s0[32][33];
  __shared__ float s1[32][33];
  const int pt = blockIdx.x * 32, dt = blockIdx.y * 32, b = blockIdx.z;
  const int tx = threadIdx.x, ty = threadIdx.y;
  const float* sb = src + ((size_t)b * Dc + dt) * HW + pt;
  const float* pb = pse + ((size_t)b * Dc + dt) * HW + pt;
  for (int i = ty; i < 32; i += 8) {
    s0[i][tx] = sb[(size_t)i * HW + tx];
    s1[i][tx] = pb[(size_t)i * HW + tx];
  }
  __syncthreads();
  const float lv = lev[dt + tx];
  for (int j = ty; j < 32; j += 8) {
    const size_t tok = (size_t)b * LQc + start + pt + j;
    x[tok * Dc + dt + tx]   = s0[tx][j];
    pos[tok * Dc + dt + tx] = s1[tx][j] + lv;
  }
}

// ---------------- fp32 tiled GEMM: C[M,N] = (A (+Apos)) @ W + bias ----------
// BM=BN=128, BK=16, 256 threads, 8x8 per thread. Optional residual / relu.
template<int ADDPOS, int RELU, int RES>
__global__ __launch_bounds__(256) void gemm128_kernel(
    const float* __restrict__ A, const float* __restrict__ Ap,
    const float* __restrict__ W, const float* __restrict__ bias,
    const float* __restrict__ res, float* __restrict__ C,
    int N, int K)
{
  __shared__ float As[16][132];   // [k][m], padded: writes 2-way, reads free
  __shared__ float Bs[16][128];   // [k][pos], pos = j*64 + tx*4 + e
  const int t  = threadIdx.x;
  const int tx = t & 15, ty = t >> 4;
  const int bm = blockIdx.y * 128;
  const int bn = blockIdx.x * 128;

  float acc[8][8];
#pragma unroll
  for (int i = 0; i < 8; ++i)
#pragma unroll
    for (int j = 0; j < 8; ++j) acc[i][j] = 0.f;

  const int arow = t >> 2;          // 0..63
  const int acol = (t & 3) * 4;     // 0,4,8,12
  const int brow = t >> 5;          // 0..7
  const int bcol = (t & 31) * 4;    // 0..124
  const int bj   = (bcol >> 2) & 1;
  const int bpos = bj * 64 + (bcol >> 3) * 4;

  for (int k0 = 0; k0 < K; k0 += 16) {
#pragma unroll
    for (int h = 0; h < 2; ++h) {
      const int row = arow + h * 64;
      float4 v = *(const float4*)(A + (size_t)(bm + row) * K + k0 + acol);
      if (ADDPOS) {
        const float4 vp = *(const float4*)(Ap + (size_t)(bm + row) * K + k0 + acol);
        v.x += vp.x; v.y += vp.y; v.z += vp.z; v.w += vp.w;
      }
      As[acol + 0][row] = v.x;
      As[acol + 1][row] = v.y;
      As[acol + 2][row] = v.z;
      As[acol + 3][row] = v.w;
    }
#pragma unroll
    for (int h = 0; h < 2; ++h) {
      const int row = brow + h * 8;
      const float4 v = *(const float4*)(W + (size_t)(k0 + row) * N + bn + bcol);
      Bs[row][bpos + 0] = v.x;
      Bs[row][bpos + 1] = v.y;
      Bs[row][bpos + 2] = v.z;
      Bs[row][bpos + 3] = v.w;
    }
    __syncthreads();
#pragma unroll
    for (int k = 0; k < 16; ++k) {
      float av[8], bw[8];
      { const float4 v = *(const float4*)&As[k][ty * 8];     av[0]=v.x; av[1]=v.y; av[2]=v.z; av[3]=v.w; }
      { const float4 v = *(const float4*)&As[k][ty * 8 + 4]; av[4]=v.x; av[5]=v.y; av[6]=v.z; av[7]=v.w; }
      { const float4 v = *(const float4*)&Bs[k][tx * 4];      bw[0]=v.x; bw[1]=v.y; bw[2]=v.z; bw[3]=v.w; }
      { const float4 v = *(const float4*)&Bs[k][64 + tx * 4]; bw[4]=v.x; bw[5]=v.y; bw[6]=v.z; bw[7]=v.w; }
#pragma unroll
      for (int i = 0; i < 8; ++i)
#pragma unroll
        for (int j = 0; j < 8; ++j)
          acc[i][j] += av[i] * bw[j];
    }
    __syncthreads();
  }

  float bb[8];
  { const float4 v = *(const float4*)(bias + bn + tx * 8);     bb[0]=v.x; bb[1]=v.y; bb[2]=v.z; bb[3]=v.w; }
  { const float4 v = *(const float4*)(bias + bn + tx * 8 + 4); bb[4]=v.x; bb[5]=v.y; bb[6]=v.z; bb[7]=v.w; }
#pragma unroll
  for (int i = 0; i < 8; ++i) {
    const size_t row = bm + ty * 8 + i;
    float o[8];
#pragma unroll
    for (int j = 0; j < 8; ++j) o[j] = acc[i][j] + bb[j];
    if (RES) {
      { const float4 v = *(const float4*)(res + row * N + bn + tx * 8);     o[0]+=v.x; o[1]+=v.y; o[2]+=v.z; o[3]+=v.w; }
      { const float4 v = *(const float4*)(res + row * N + bn + tx * 8 + 4); o[4]+=v.x; o[5]+=v.y; o[6]+=v.z; o[7]+=v.w; }
    }
    if (RELU) {
#pragma unroll
      for (int j = 0; j < 8; ++j) o[j] = fmaxf(o[j], 0.f);
    }
    float4 o0, o1;
    o0.x=o[0]; o0.y=o[1]; o0.z=o[2]; o0.w=o[3];
    o1.x=o[4]; o1.y=o[5]; o1.z=o[6]; o1.w=o[7];
    *(float4*)(C + row * N + bn + tx * 8)     = o0;
    *(float4*)(C + row * N + bn + tx * 8 + 4) = o1;
  }
}

// ---------------- deformable sampling + fused softmax -----------------------
// 32 lanes per (tok, head); lane = channel dh. 8 groups per 256-thread block.
// `out` may alias `off` — same-thread, same-address read-then-write only.
__global__ __launch_bounds__(256) void msdeform_kernel(
    const float* __restrict__ val, const float* __restrict__ off,
    const float* __restrict__ attl, float* __restrict__ out)
{
  const int t    = threadIdx.x;
  const int g    = t >> 5;
  const int lane = t & 31;
  const int gid  = blockIdx.x * 8 + g;   // tok*8 + head
  const int head = gid & 7;
  const int tok  = gid >> 3;
  const int b    = tok / LQc;
  const int q    = tok - b * LQc;

  int sq, lgW;
  if (q < 4096)      { sq = 0;    lgW = 6; }
  else if (q < 5120) { sq = 4096; lgW = 5; }
  else if (q < 5376) { sq = 5120; lgW = 4; }
  else               { sq = 5376; lgW = 3; }
  const int pix = q - sq;
  const int Wq  = 1 << lgW;
  const float refx = ((pix & (Wq - 1)) + 0.5f) / (float)Wq;
  const float refy = ((pix >> lgW) + 0.5f) / (float)Wq;

  const float offv = off[(size_t)tok * 256 + head * 32 + lane];

  float lg = attl[(size_t)tok * 128 + head * 16 + (lane & 15)];
  float mx = lg;
#pragma unroll
  for (int msk = 8; msk >= 1; msk >>= 1) mx = fmaxf(mx, __shfl_xor(mx, msk));
  const float e = __expf(lg - mx);
  float ssum = e;
#pragma unroll
  for (int msk = 8; msk >= 1; msk >>= 1) ssum += __shfl_xor(ssum, msk);
  const float wn = e / ssum;

  const int hch = head * 32 + lane;
  const size_t vbase = (size_t)(b * LQc) * 256 + hch;

  const int   levS[4]  = {64, 32, 16, 8};
  const int   levSt[4] = {0, 4096, 5120, 5376};
  const float levI[4]  = {1.f/64.f, 1.f/32.f, 1.f/16.f, 1.f/8.f};

  float acc = 0.f;
#pragma unroll
  for (int s = 0; s < 16; ++s) {
    const int l = s >> 2;
    const float ox = __shfl(offv, 2 * s, 32);
    const float oy = __shfl(offv, 2 * s + 1, 32);
    const float ws = __shfl(wn, s, 32);
    const int   S  = levS[l];
    const float Sf = (float)S;
    const float fx = (refx + ox * levI[l]) * Sf - 0.5f;
    const float fy = (refy + oy * levI[l]) * Sf - 0.5f;
    const float x0f = floorf(fx), y0f = floorf(fy);
    const float dx = fx - x0f, dy = fy - y0f;
    const int x0 = (int)x0f, y0 = (int)y0f;
    float sv = 0.f;
#pragma unroll
    for (int c = 0; c < 4; ++c) {
      const int xi = x0 + (c & 1);
      const int yi = y0 + (c >> 1);
      if (xi >= 0 && xi < S && yi >= 0 && yi < S) {
        const float wc = ((c & 1) ? dx : 1.f - dx) * ((c >> 1) ? dy : 1.f - dy);
        sv += wc * val[vbase + (size_t)(levSt[l] + yi * S + xi) * 256];
      }
    }
    acc += ws * sv;
  }
  out[(size_t)tok * 256 + hch] = acc;
}

// ---------------- LayerNorm (one wave per 256-wide token row) ---------------
__global__ __launch_bounds__(256) void ln_kernel(
    const float* __restrict__ in, const float* __restrict__ g,
    const float* __restrict__ b, float* __restrict__ out)
{
  const int w    = threadIdx.x >> 6;
  const int lane = threadIdx.x & 63;
  const size_t tok = (size_t)blockIdx.x * 4 + w;
  const float4 v = *(const float4*)(in + tok * 256 + lane * 4);
  float s  = v.x + v.y + v.z + v.w;
  float s2 = v.x*v.x + v.y*v.y + v.z*v.z + v.w*v.w;
#pragma unroll
  for (int msk = 32; msk >= 1; msk >>= 1) {
    s  += __shfl_xor(s, msk);
    s2 += __shfl_xor(s2, msk);
  }
  const float mu  = s * (1.f / 256.f);
  const float var = s2 * (1.f / 256.f) - mu * mu;
  const float inv = rsqrtf(var + 1e-5f);
  const float4 gg = *(const float4*)(g + lane * 4);
  const float4 bb = *(const float4*)(b + lane * 4);
  float4 o;
  o.x = (v.x - mu) * inv * gg.x + bb.x;
  o.y = (v.y - mu) * inv * gg.y + bb.y;
  o.z = (v.z - mu) * inv * gg.z + bb.z;
  o.w = (v.w - mu) * inv * gg.w + bb.w;
  *(float4*)(out + tok * 256 + lane * 4) = o;
}

// ---------------------------------------------------------------------------
extern "C" void kernel_launch(void* const* d_in, const int* in_sizes, int n_in,
                              void* d_out, int out_size, void* d_ws, size_t ws_size,
                              hipStream_t stream)
{
  (void)in_sizes; (void)n_in; (void)out_size; (void)ws_size;
  const float* src[4] = {(const float*)d_in[0], (const float*)d_in[2],
                         (const float*)d_in[4], (const float*)d_in[6]};
  const float* pse[4] = {(const float*)d_in[1], (const float*)d_in[3],
                         (const float*)d_in[5], (const float*)d_in[7]};
  const float* le   = (const float*)d_in[8];
  const float* Wv   = (const float*)d_in[9];
  const float* bv   = (const float*)d_in[10];
  const float* Wo   = (const float*)d_in[11];
  const float* bo   = (const float*)d_in[12];
  const float* Wa   = (const float*)d_in[13];
  const float* ba   = (const float*)d_in[14];
  const float* Wout = (const float*)d_in[15];
  const float* bout = (const float*)d_in[16];
  const float* ln1g = (const float*)d_in[17];
  const float* ln1b = (const float*)d_in[18];
  const float* W1   = (const float*)d_in[19];
  const float* b1   = (const float*)d_in[20];
  const float* W2   = (const float*)d_in[21];
  const float* b2   = (const float*)d_in[22];
  const float* ln2g = (const float*)d_in[23];
  const float* ln2b = (const float*)d_in[24];

  // X lives in d_out (fully rewritten by flatten every call).
  float* bufX   = (float*)d_out;
  float* bufPos = (float*)d_ws;                       // 256/tok
  float* bufT   = bufPos + (size_t)NTOK * 256;        // 256/tok (aliases val)
  float* bufOff = bufT   + (size_t)NTOK * 256;        // 256/tok (off, acc, H-chunk)
  float* bufAtt = bufOff + (size_t)NTOK * 256;        // 128/tok
  float* bufVal = bufT;
  float* bufAcc = bufOff;   // msdeform same-addr RMW per thread
  float* bufH   = bufOff;   // FFN hidden chunk (10880 rows x 1024)

  const int HWs[4]    = {4096, 1024, 256, 64};
  const int starts[4] = {0, 4096, 5120, 5376};
  for (int l = 0; l < 4; ++l) {
    dim3 grid(HWs[l] / 32, 8, 8);
    flatten_level_kernel<<<grid, dim3(32, 8), 0, stream>>>(
        src[l], pse[l], le + l * 256, bufX, bufPos, HWs[l], starts[l]);
  }

  const int CHTOK = 10880;                 // FFN token-chunk (4 chunks)
  for (int i = 0; i < 6; ++i) {
    // value = x @ Wv + bv            -> bufVal (=T region)
    gemm128_kernel<0,0,0><<<dim3(2, 340), 256, 0, stream>>>(
        bufX, nullptr, Wv + (size_t)i * 65536, bv + i * 256, nullptr, bufVal, 256, 256);
    // off = (x+pos) @ Wo + bo        -> bufOff
    gemm128_kernel<1,0,0><<<dim3(2, 340), 256, 0, stream>>>(
        bufX, bufPos, Wo + (size_t)i * 65536, bo + i * 256, nullptr, bufOff, 256, 256);
    // attn logits = (x+pos) @ Wa + ba -> bufAtt
    gemm128_kernel<1,0,0><<<dim3(1, 340), 256, 0, stream>>>(
        bufX, bufPos, Wa + (size_t)i * 32768, ba + i * 128, nullptr, bufAtt, 128, 256);
    // deformable sampling (fused softmax): acc overwrites off in-place
    msdeform_kernel<<<NTOK, 256, 0, stream>>>(bufVal, bufOff, bufAtt, bufAcc);
    // T = acc @ Wout + bout + x      (val region now dead -> becomes T)
    gemm128_kernel<0,0,1><<<dim3(2, 340), 256, 0, stream>>>(
        bufAcc, nullptr, Wout + (size_t)i * 65536, bout + i * 256, bufX, bufT, 256, 256);
    // x = LN1(T)
    ln_kernel<<<NTOK / 4, 256, 0, stream>>>(bufT, ln1g + i * 256, ln1b + i * 256, bufX);
    // FFN in 4 token-chunks; hidden chunk reuses off/acc region
    for (int c = 0; c < 4; ++c) {
      const size_t coff = (size_t)c * CHTOK * 256;
      gemm128_kernel<0,1,0><<<dim3(8, 85), 256, 0, stream>>>(
          bufX + coff, nullptr, W1 + (size_t)i * 262144, b1 + i * 1024, nullptr,
          bufH, 1024, 256);
      gemm128_kernel<0,0,1><<<dim3(2, 85), 256, 0, stream>>>(
          bufH, nullptr, W2 + (size_t)i * 262144, b2 + i * 256, bufX + coff,
          bufT + coff, 256, 1024);
    }
    // x = LN2(T)  (x == d_out, so the final layer's result lands in d_out)
    ln_kernel<<<NTOK / 4, 256, 0, stream>>>(bufT, ln2g + i * 256, ln2b + i * 256, bufX);
  }
}

// Round 5
// 4484.271 us; speedup vs baseline: 2.1816x; 2.1816x over previous
//
#include <hip/hip_runtime.h>
#include <math.h>

// ---------------------------------------------------------------------------
// MSDeformAttn encoder, 6 layers. Round 4: GEMMs moved to bf16 MFMA
// (mfma_f32_16x16x32_bf16), weights pre-transposed to bf16 [N][K] once per
// call, activations produced in bf16 by producer kernels. msdeform unchanged
// except bf16 off/att in, bf16 acc out. Workspace 143MB (<156MB proven).
//
// NTOK=43520, D=256, NH=8, DH=32, NL=4, NP=4, DFF=1024, 6 layers.
//
// ws regions (bytes):
//  R0 posb   bf16 [NTOK][256]            @ 0          22,282,240
//  R1 T/val  fp32 [NTOK][256]            @ 22282240   44,564,480
//  R2 off_bf/hb                          @ 66846720   22,282,240
//  R3 att_bf/x1b                         @ 89128960   22,282,240
//  R4 qb/accb bf16 [NTOK][256]           @ 111411200  22,282,240
//  R5 weightsT bf16                      @ 133693440   9,043,968
//  total 142,737,408
// x fp32 lives in d_out.
// ---------------------------------------------------------------------------

#define NTOK 43520
#define LQc  5440
#define Dc   256

typedef __attribute__((ext_vector_type(4))) float f32x4;
typedef __attribute__((ext_vector_type(8))) short bf16x8;

static __device__ __forceinline__ short f2bf(float f) {
  union { float f; unsigned u; } v; v.f = f;
  unsigned r = v.u + 0x7fff + ((v.u >> 16) & 1);   // RNE
  return (short)(r >> 16);
}
static __device__ __forceinline__ float bf2f(short s) {
  union { unsigned u; float f; } v; v.u = ((unsigned)(unsigned short)s) << 16;
  return v.f;
}

// ---------------- flatten: (B,C,H,W) -> x fp32, posb bf16, qb bf16 ----------
__global__ __launch_bounds__(256) void flatten_level_kernel(
    const float* __restrict__ src, const float* __restrict__ pse,
    const float* __restrict__ lev, float* __restrict__ x,
    short* __restrict__ posb, short* __restrict__ qb,
    int HW, int start)
{
  __shared__ float s0[32][33];
  __shared__ float s1[32][33];
  const int pt = blockIdx.x * 32, dt = blockIdx.y * 32, b = blockIdx.z;
  const int tx = threadIdx.x, ty = threadIdx.y;
  const float* sb = src + ((size_t)b * Dc + dt) * HW + pt;
  const float* pb = pse + ((size_t)b * Dc + dt) * HW + pt;
  for (int i = ty; i < 32; i += 8) {
    s0[i][tx] = sb[(size_t)i * HW + tx];
    s1[i][tx] = pb[(size_t)i * HW + tx];
  }
  __syncthreads();
  const float lv = lev[dt + tx];
  for (int j = ty; j < 32; j += 8) {
    const size_t tok = (size_t)b * LQc + start + pt + j;
    const float xv = s0[tx][j];
    const float pv = s1[tx][j] + lv;
    x[tok * Dc + dt + tx]    = xv;
    posb[tok * Dc + dt + tx] = f2bf(pv);
    qb[tok * Dc + dt + tx]   = f2bf(xv + pv);
  }
}

// ---------------- weight transpose+convert: W[K][N] fp32 -> Wt[N][K] bf16 ---
__global__ __launch_bounds__(256) void wtrans_kernel(
    const float* __restrict__ W, short* __restrict__ Wt, int N, int K)
{
  __shared__ float s[32][33];
  W  += (size_t)blockIdx.z * N * K;
  Wt += (size_t)blockIdx.z * N * K;
  const int n0 = blockIdx.x * 32, k0 = blockIdx.y * 32;
  const int tx = threadIdx.x, ty = threadIdx.y;
  for (int i = ty; i < 32; i += 8) s[i][tx] = W[(size_t)(k0 + i) * N + n0 + tx];
  __syncthreads();
  for (int j = ty; j < 32; j += 8)
    Wt[(size_t)(n0 + j) * K + k0 + tx] = f2bf(s[tx][j]);
}

// ---------------- bf16 MFMA GEMM: C[M,N] = A[M,K] @ Wt[N,K]^T + bias --------
// 128x128 tile, BK=32, 256 thr (4 waves 2x2), 4x4 frags of 16x16x32 per wave.
// LDS [row][32] bf16 with byte^=((row&7)<<4) XOR swizzle on 16B chunks.
template<int RELU, int RES, int OUTBF, int ACVT>
__global__ __launch_bounds__(256) void gemm_mfma_kernel(
    const void* __restrict__ Aptr, const short* __restrict__ Wt,
    const float* __restrict__ bias, const float* __restrict__ res,
    void* __restrict__ C, int N, int K)
{
  __shared__ short As[128 * 32];
  __shared__ short Bs[128 * 32];
  const int t = threadIdx.x;
  const int wave = t >> 6, lane = t & 63;
  const int wr = wave >> 1, wc = wave & 1;
  const int l15 = lane & 15, lk = lane >> 4;
  const int bm = blockIdx.y * 128, bn = blockIdx.x * 128;

  f32x4 acc[4][4];
#pragma unroll
  for (int i = 0; i < 4; ++i)
#pragma unroll
    for (int j = 0; j < 4; ++j) acc[i][j] = (f32x4)0.f;

  const int sr = t >> 1;                 // stage row 0..127
  const int sh = t & 1;                  // 16-elem half
  const int swz = (sr & 7) << 4;
  const int wb0 = (sr * 64 + sh * 32 + 0)  ^ swz;
  const int wb1 = (sr * 64 + sh * 32 + 16) ^ swz;

  // precompute fragment read byte offsets
  int aoff[4], boff[4];
#pragma unroll
  for (int i = 0; i < 4; ++i) {
    const int ar = wr * 64 + i * 16 + l15;
    aoff[i] = (ar * 64 + lk * 16) ^ ((ar & 7) << 4);
    const int bc = wc * 64 + i * 16 + l15;
    boff[i] = (bc * 64 + lk * 16) ^ ((bc & 7) << 4);
  }

  for (int k0 = 0; k0 < K; k0 += 32) {
    int4 a0, a1, b0, b1;
    if (ACVT) {
      const float* Af = (const float*)Aptr + (size_t)(bm + sr) * K + k0 + sh * 16;
      short sv[16] __attribute__((aligned(16)));
      const float4 f0 = *(const float4*)(Af + 0);
      const float4 f1 = *(const float4*)(Af + 4);
      const float4 f2 = *(const float4*)(Af + 8);
      const float4 f3 = *(const float4*)(Af + 12);
      sv[0]=f2bf(f0.x); sv[1]=f2bf(f0.y); sv[2]=f2bf(f0.z); sv[3]=f2bf(f0.w);
      sv[4]=f2bf(f1.x); sv[5]=f2bf(f1.y); sv[6]=f2bf(f1.z); sv[7]=f2bf(f1.w);
      sv[8]=f2bf(f2.x); sv[9]=f2bf(f2.y); sv[10]=f2bf(f2.z); sv[11]=f2bf(f2.w);
      sv[12]=f2bf(f3.x); sv[13]=f2bf(f3.y); sv[14]=f2bf(f3.z); sv[15]=f2bf(f3.w);
      a0 = *(const int4*)&sv[0];
      a1 = *(const int4*)&sv[8];
    } else {
      const int4* Ab = (const int4*)((const short*)Aptr + (size_t)(bm + sr) * K + k0 + sh * 16);
      a0 = Ab[0]; a1 = Ab[1];
    }
    {
      const int4* Bb = (const int4*)(Wt + (size_t)(bn + sr) * K + k0 + sh * 16);
      b0 = Bb[0]; b1 = Bb[1];
    }
    __syncthreads();   // previous iteration's reads complete
    *(int4*)((char*)As + wb0) = a0;
    *(int4*)((char*)As + wb1) = a1;
    *(int4*)((char*)Bs + wb0) = b0;
    *(int4*)((char*)Bs + wb1) = b1;
    __syncthreads();

    bf16x8 af[4], bf[4];
#pragma unroll
    for (int i = 0; i < 4; ++i) {
      af[i] = *(const bf16x8*)((const char*)As + aoff[i]);
      bf[i] = *(const bf16x8*)((const char*)Bs + boff[i]);
    }
#pragma unroll
    for (int mi = 0; mi < 4; ++mi)
#pragma unroll
      for (int ni = 0; ni < 4; ++ni)
        acc[mi][ni] = __builtin_amdgcn_mfma_f32_16x16x32_bf16(af[mi], bf[ni], acc[mi][ni], 0, 0, 0);
  }

  // epilogue: C[row][col], col=lane&15 based, row=(lane>>4)*4+r based
  const int crow0 = bm + wr * 64 + lk * 4;
  const int ccol0 = bn + wc * 64 + l15;
#pragma unroll
  for (int ni = 0; ni < 4; ++ni) {
    const int col = ccol0 + ni * 16;
    const float bs = bias[col];
#pragma unroll
    for (int mi = 0; mi < 4; ++mi) {
      const int row0 = crow0 + mi * 16;
#pragma unroll
      for (int r = 0; r < 4; ++r) {
        const size_t idx = (size_t)(row0 + r) * N + col;
        float o = acc[mi][ni][r] + bs;
        if (RES) o += res[idx];
        if (RELU) o = fmaxf(o, 0.f);
        if (OUTBF) ((short*)C)[idx] = f2bf(o);
        else       ((float*)C)[idx] = o;
      }
    }
  }
}

// ---------------- deformable sampling + fused softmax (bf16 I/O) ------------
__global__ __launch_bounds__(256) void msdeform_kernel(
    const float* __restrict__ val, const short* __restrict__ off,
    const short* __restrict__ attl, short* __restrict__ outb)
{
  const int t    = threadIdx.x;
  const int g    = t >> 5;
  const int lane = t & 31;
  const int gid  = blockIdx.x * 8 + g;   // tok*8 + head
  const int head = gid & 7;
  const int tok  = gid >> 3;
  const int b    = tok / LQc;
  const int q    = tok - b * LQc;

  int sq, lgW;
  if (q < 4096)      { sq = 0;    lgW = 6; }
  else if (q < 5120) { sq = 4096; lgW = 5; }
  else if (q < 5376) { sq = 5120; lgW = 4; }
  else               { sq = 5376; lgW = 3; }
  const int pix = q - sq;
  const int Wq  = 1 << lgW;
  const float refx = ((pix & (Wq - 1)) + 0.5f) / (float)Wq;
  const float refy = ((pix >> lgW) + 0.5f) / (float)Wq;

  const float offv = bf2f(off[(size_t)tok * 256 + head * 32 + lane]);

  float lg = bf2f(attl[(size_t)tok * 128 + head * 16 + (lane & 15)]);
  float mx = lg;
#pragma unroll
  for (int msk = 8; msk >= 1; msk >>= 1) mx = fmaxf(mx, __shfl_xor(mx, msk));
  const float e = __expf(lg - mx);
  float ssum = e;
#pragma unroll
  for (int msk = 8; msk >= 1; msk >>= 1) ssum += __shfl_xor(ssum, msk);
  const float wn = e / ssum;

  const int hch = head * 32 + lane;
  const size_t vbase = (size_t)(b * LQc) * 256 + hch;

  const int   levS[4]  = {64, 32, 16, 8};
  const int   levSt[4] = {0, 4096, 5120, 5376};
  const float levI[4]  = {1.f/64.f, 1.f/32.f, 1.f/16.f, 1.f/8.f};

  float acc = 0.f;
#pragma unroll
  for (int s = 0; s < 16; ++s) {
    const int l = s >> 2;
    const float ox = __shfl(offv, 2 * s, 32);
    const float oy = __shfl(offv, 2 * s + 1, 32);
    const float ws = __shfl(wn, s, 32);
    const int   S  = levS[l];
    const float Sf = (float)S;
    const float fx = (refx + ox * levI[l]) * Sf - 0.5f;
    const float fy = (refy + oy * levI[l]) * Sf - 0.5f;
    const float x0f = floorf(fx), y0f = floorf(fy);
    const float dx = fx - x0f, dy = fy - y0f;
    const int x0 = (int)x0f, y0 = (int)y0f;
    float sv = 0.f;
#pragma unroll
    for (int c = 0; c < 4; ++c) {
      const int xi = x0 + (c & 1);
      const int yi = y0 + (c >> 1);
      if (xi >= 0 && xi < S && yi >= 0 && yi < S) {
        const float wc = ((c & 1) ? dx : 1.f - dx) * ((c >> 1) ? dy : 1.f - dy);
        sv += wc * val[vbase + (size_t)(levSt[l] + yi * S + xi) * 256];
      }
    }
    acc += ws * sv;
  }
  outb[(size_t)tok * 256 + hch] = f2bf(acc);
}

// ---------------- LayerNorm: fp32 out + optional bf16 out / q=x+pos bf16 ----
template<int WB, int WQ>
__global__ __launch_bounds__(256) void ln_kernel(
    const float* __restrict__ in, const float* __restrict__ g,
    const float* __restrict__ b, float* __restrict__ outF,
    short* __restrict__ outB, const short* __restrict__ posb,
    short* __restrict__ outQ)
{
  const int w    = threadIdx.x >> 6;
  const int lane = threadIdx.x & 63;
  const size_t tok = (size_t)blockIdx.x * 4 + w;
  const float4 v = *(const float4*)(in + tok * 256 + lane * 4);
  float s  = v.x + v.y + v.z + v.w;
  float s2 = v.x*v.x + v.y*v.y + v.z*v.z + v.w*v.w;
#pragma unroll
  for (int msk = 32; msk >= 1; msk >>= 1) {
    s  += __shfl_xor(s, msk);
    s2 += __shfl_xor(s2, msk);
  }
  const float mu  = s * (1.f / 256.f);
  const float var = s2 * (1.f / 256.f) - mu * mu;
  const float inv = rsqrtf(var + 1e-5f);
  const float4 gg = *(const float4*)(g + lane * 4);
  const float4 bb = *(const float4*)(b + lane * 4);
  float o[4];
  o[0] = (v.x - mu) * inv * gg.x + bb.x;
  o[1] = (v.y - mu) * inv * gg.y + bb.y;
  o[2] = (v.z - mu) * inv * gg.z + bb.z;
  o[3] = (v.w - mu) * inv * gg.w + bb.w;
  float4 of; of.x=o[0]; of.y=o[1]; of.z=o[2]; of.w=o[3];
  *(float4*)(outF + tok * 256 + lane * 4) = of;
  if (WB) {
    short sb4[4];
#pragma unroll
    for (int j = 0; j < 4; ++j) sb4[j] = f2bf(o[j]);
    *(int2*)(outB + tok * 256 + lane * 4) = *(int2*)sb4;
  }
  if (WQ) {
    short sq4[4];
#pragma unroll
    for (int j = 0; j < 4; ++j)
      sq4[j] = f2bf(o[j] + bf2f(posb[tok * 256 + lane * 4 + j]));
    *(int2*)(outQ + tok * 256 + lane * 4) = *(int2*)sq4;
  }
}

// ---------------------------------------------------------------------------
extern "C" void kernel_launch(void* const* d_in, const int* in_sizes, int n_in,
                              void* d_out, int out_size, void* d_ws, size_t ws_size,
                              hipStream_t stream)
{
  (void)in_sizes; (void)n_in; (void)out_size; (void)ws_size;
  const float* src[4] = {(const float*)d_in[0], (const float*)d_in[2],
                         (const float*)d_in[4], (const float*)d_in[6]};
  const float* pse[4] = {(const float*)d_in[1], (const float*)d_in[3],
                         (const float*)d_in[5], (const float*)d_in[7]};
  const float* le   = (const float*)d_in[8];
  const float* Wv   = (const float*)d_in[9];
  const float* bv   = (const float*)d_in[10];
  const float* Wo   = (const float*)d_in[11];
  const float* bo   = (const float*)d_in[12];
  const float* Wa   = (const float*)d_in[13];
  const float* ba   = (const float*)d_in[14];
  const float* Wout = (const float*)d_in[15];
  const float* bout = (const float*)d_in[16];
  const float* ln1g = (const float*)d_in[17];
  const float* ln1b = (const float*)d_in[18];
  const float* W1   = (const float*)d_in[19];
  const float* b1   = (const float*)d_in[20];
  const float* W2   = (const float*)d_in[21];
  const float* b2   = (const float*)d_in[22];
  const float* ln2g = (const float*)d_in[23];
  const float* ln2b = (const float*)d_in[24];

  float* xF = (float*)d_out;                       // x fp32
  char*  ws = (char*)d_ws;
  short* posb = (short*)(ws);                      // R0
  float* bufT = (float*)(ws + 22282240);           // R1 (T / val)
  short* offb = (short*)(ws + 66846720);           // R2 (off_bf / hb)
  short* attb = (short*)(ws + 89128960);           // R3 (att_bf / x1b)
  short* qb   = (short*)(ws + 111411200);          // R4 (qb / accb)
  short* wT   = (short*)(ws + 133693440);          // R5 weights
  float* bufVal = bufT;
  short* hb   = offb;
  short* x1b  = attb;
  short* accb = qb;
  short* wvT = wT, *woT = wT + 393216, *waT = wT + 786432,
       *woutT = wT + 983040, *w1T = wT + 1376256, *w2T = wT + 2949120;

  // ---- weight prep (runs every call; deterministic) ----
  wtrans_kernel<<<dim3(8, 8, 6),  dim3(32, 8), 0, stream>>>(Wv,   wvT,   256, 256);
  wtrans_kernel<<<dim3(8, 8, 6),  dim3(32, 8), 0, stream>>>(Wo,   woT,   256, 256);
  wtrans_kernel<<<dim3(4, 8, 6),  dim3(32, 8), 0, stream>>>(Wa,   waT,   128, 256);
  wtrans_kernel<<<dim3(8, 8, 6),  dim3(32, 8), 0, stream>>>(Wout, woutT, 256, 256);
  wtrans_kernel<<<dim3(32, 8, 6), dim3(32, 8), 0, stream>>>(W1,   w1T,  1024, 256);
  wtrans_kernel<<<dim3(8, 32, 6), dim3(32, 8), 0, stream>>>(W2,   w2T,   256, 1024);

  const int HWs[4]    = {4096, 1024, 256, 64};
  const int starts[4] = {0, 4096, 5120, 5376};
  for (int l = 0; l < 4; ++l) {
    dim3 grid(HWs[l] / 32, 8, 8);
    flatten_level_kernel<<<grid, dim3(32, 8), 0, stream>>>(
        src[l], pse[l], le + l * 256, xF, posb, qb, HWs[l], starts[l]);
  }

  const int CHTOK = 10880;
  for (int i = 0; i < 6; ++i) {
    // val = x @ Wv + bv (A fp32 converted in staging)
    gemm_mfma_kernel<0,0,0,1><<<dim3(2, 340), 256, 0, stream>>>(
        xF, wvT + (size_t)i * 65536, bv + i * 256, nullptr, bufVal, 256, 256);
    // off = q @ Wo + bo  -> bf16
    gemm_mfma_kernel<0,0,1,0><<<dim3(2, 340), 256, 0, stream>>>(
        qb, woT + (size_t)i * 65536, bo + i * 256, nullptr, offb, 256, 256);
    // att = q @ Wa + ba  -> bf16
    gemm_mfma_kernel<0,0,1,0><<<dim3(1, 340), 256, 0, stream>>>(
        qb, waT + (size_t)i * 32768, ba + i * 128, nullptr, attb, 128, 256);
    // sampling (writes accb bf16 into qb region — qb dead until LN2 rewrites)
    msdeform_kernel<<<NTOK, 256, 0, stream>>>(bufVal, offb, attb, accb);
    // T = accb @ Wout + bout + x
    gemm_mfma_kernel<0,1,0,0><<<dim3(2, 340), 256, 0, stream>>>(
        accb, woutT + (size_t)i * 65536, bout + i * 256, xF, bufT, 256, 256);
    // x' = LN1(T): fp32 -> xF, bf16 -> x1b
    ln_kernel<1,0><<<NTOK / 4, 256, 0, stream>>>(
        bufT, ln1g + i * 256, ln1b + i * 256, xF, x1b, nullptr, nullptr);
    // FFN in 4 chunks: h = relu(x1b@W1+b1) bf16; T = h@W2+b2+x'
    for (int c = 0; c < 4; ++c) {
      const size_t co = (size_t)c * CHTOK * 256;
      gemm_mfma_kernel<1,0,1,0><<<dim3(8, 85), 256, 0, stream>>>(
          x1b + co, w1T + (size_t)i * 262144, b1 + i * 1024, nullptr, hb, 1024, 256);
      gemm_mfma_kernel<0,1,0,0><<<dim3(2, 85), 256, 0, stream>>>(
          hb, w2T + (size_t)i * 262144, b2 + i * 256, xF + co, bufT + co, 256, 1024);
    }
    // x'' = LN2(T): fp32 -> xF (d_out), qb = bf16(x''+pos) for next layer
    ln_kernel<0,1><<<NTOK / 4, 256, 0, stream>>>(
        bufT, ln2g + i * 256, ln2b + i * 256, xF, nullptr, posb, qb);
  }
}